// Round 1
// baseline (593.962 us; speedup 1.0000x reference)
//
#include <hip/hip_runtime.h>
#include <hip/hip_bf16.h>
#include <math.h>

#define K_CTX 64
#define D_DIM 128
#define DS 200
#define CAND 256
#define EPS_F 1e-8f
#define GAMMA 0.5f

__device__ __forceinline__ float wave_sum(float v) {
#pragma unroll
  for (int o = 32; o > 0; o >>= 1) v += __shfl_xor(v, o, 64);
  return v;
}
__device__ __forceinline__ float wave_max(float v) {
#pragma unroll
  for (int o = 32; o > 0; o >>= 1) v = fmaxf(v, __shfl_xor(v, o, 64));
  return v;
}

// Kernel 1: AM[k][j] = sum_i table[t1_ctx[k]][i] * att_mat[i][j]
__global__ __launch_bounds__(128, 1) void am_kernel(
    const float* __restrict__ table, const float* __restrict__ att_mat,
    const int* __restrict__ t1_ctx, float* __restrict__ AM) {
  __shared__ float sA[D_DIM];
  const int k = blockIdx.x;
  const int j = threadIdx.x;
  const size_t row = (size_t)t1_ctx[k] * D_DIM;
  sA[j] = table[row + j];
  __syncthreads();
  float s = 0.f;
#pragma unroll 8
  for (int i = 0; i < D_DIM; ++i)
    s = fmaf(sA[i], att_mat[(size_t)i * D_DIM + j], s);
  AM[k * D_DIM + j] = s;
}

// Kernel 2: one block per candidate c.
__global__ __launch_bounds__(256, 1) void cand_kernel(
    const float* __restrict__ table, const float* __restrict__ str_t1,
    const float* __restrict__ str_t2s, const float* __restrict__ W_bi,
    const float* __restrict__ b_bi, const int* __restrict__ t1_ctx,
    const int* __restrict__ t2_ctx, const float* __restrict__ AM,
    float* __restrict__ out) {
  const int c = blockIdx.x;
  const int tid = threadIdx.x;
  const int lane = tid & 63;
  const int wv = tid >> 6;  // 0..3

  __shared__ float sAM[K_CTX * D_DIM];  // 32 KB, float4-aligned
  __shared__ int t2g[K_CTX];
  __shared__ int t1g[K_CTX];
  __shared__ float colpart[4][K_CTX];
  __shared__ float rowsum[K_CTX];
  __shared__ float rows[K_CTX];
  __shared__ float cols[K_CTX];
  __shared__ float sNA[D_DIM];
  __shared__ float sNB[D_DIM];
  __shared__ float wred[4];
  __shared__ float scal[3];  // str_dot, n2sq, n1sq

  if (tid < K_CTX) {
    t2g[tid] = t2_ctx[c * K_CTX + tid];
    t1g[tid] = t1_ctx[tid];
  }
  __syncthreads();

  // Register-cache this thread's B row (m = lane). All 4 waves load the same
  // 64 rows -> L1-hot after first wave; rows also reused by new_B later.
  const int m = lane;
  const float4* browp = (const float4*)(table + (size_t)t2g[m] * D_DIM);
  float4 b4[32];
#pragma unroll
  for (int i4 = 0; i4 < 32; ++i4) b4[i4] = browp[i4];

  // Stage AM into LDS: 2048 float4, 8 per thread (coalesced).
  {
    const float4* amp = (const float4*)AM;
    float4* samp = (float4*)sAM;
#pragma unroll
    for (int t = 0; t < 8; ++t) samp[tid + 256 * t] = amp[tid + 256 * t];
  }
  __syncthreads();

  // S[k][m] = tanh(dot(AM[k], B[m])); this wave handles k in [kbase, kbase+16)
  const int kbase = wv * 16;
  float acc[16];
#pragma unroll
  for (int kk = 0; kk < 16; ++kk) acc[kk] = 0.f;

  const float4* sAM4 = (const float4*)sAM;
#pragma unroll
  for (int i4 = 0; i4 < 32; ++i4) {
    const float4 bv = b4[i4];
#pragma unroll
    for (int kk = 0; kk < 16; ++kk) {
      const float4 am = sAM4[(kbase + kk) * 32 + i4];  // wave-uniform broadcast
      acc[kk] = fmaf(am.x, bv.x, acc[kk]);
      acc[kk] = fmaf(am.y, bv.y, acc[kk]);
      acc[kk] = fmaf(am.z, bv.z, acc[kk]);
      acc[kk] = fmaf(am.w, bv.w, acc[kk]);
    }
  }

  float cp = 0.f;
#pragma unroll
  for (int kk = 0; kk < 16; ++kk) {
    const float sv = tanhf(acc[kk]);
    cp += sv;
    const float rs = wave_sum(sv);  // sum over m (64 lanes)
    if (lane == 0) rowsum[kbase + kk] = rs;
  }
  colpart[wv][m] = cp;
  __syncthreads();

  // Softmaxes on waves 0/1; string branch on waves 2/3 (concurrent).
  if (wv == 0) {
    const float rm = rowsum[lane] * (1.f / 64.f);
    const float mx = wave_max(rm);
    const float e = expf(rm - mx);
    const float s = wave_sum(e);
    rows[lane] = e / s;
  } else if (wv == 1) {
    const float csum = colpart[0][lane] + colpart[1][lane] + colpart[2][lane] +
                       colpart[3][lane];
    const float cm = csum * (1.f / 64.f);
    const float mx = wave_max(cm);
    const float e = expf(cm - mx);
    const float s = wave_sum(e);
    cols[lane] = e / s;
  } else if (wv == 2) {
    float dot = 0.f, n2 = 0.f;
    for (int i = lane; i < DS; i += 64) {
      const float a = str_t2s[c * DS + i];
      const float b = str_t1[i];
      dot = fmaf(a, b, dot);
      n2 = fmaf(a, a, n2);
    }
    dot = wave_sum(dot);
    n2 = wave_sum(n2);
    if (lane == 0) { scal[0] = dot; scal[1] = n2; }
  } else {
    float n1 = 0.f;
    for (int i = lane; i < DS; i += 64) {
      const float b = str_t1[i];
      n1 = fmaf(b, b, n1);
    }
    n1 = wave_sum(n1);
    if (lane == 0) scal[2] = n1;
  }
  __syncthreads();

  // new_A[j] = sum_k rows[k]*A[k][j]  (waves 0,1)
  // new_B[j] = sum_m cols[m]*B[m][j]  (waves 2,3) -- table rows are L1/L2-hot
  if (tid < 128) {
    const int j = tid;
    float na = 0.f;
#pragma unroll 8
    for (int k = 0; k < K_CTX; ++k)
      na = fmaf(rows[k], table[(size_t)t1g[k] * D_DIM + j], na);
    sNA[j] = na;
  } else {
    const int j = tid - 128;
    float nb = 0.f;
#pragma unroll 8
    for (int mm = 0; mm < K_CTX; ++mm)
      nb = fmaf(cols[mm], table[(size_t)t2g[mm] * D_DIM + j], nb);
    sNB[j] = nb;
  }
  __syncthreads();

  // con = sum_e (sum_d new_A[d]*W[d][e]) * new_B[e]
  float contrib = 0.f;
  if (tid < 128) {
    const int e = tid;
    float t = 0.f;
#pragma unroll 8
    for (int dd = 0; dd < D_DIM; ++dd)
      t = fmaf(sNA[dd], W_bi[dd * D_DIM + e], t);
    contrib = t * sNB[e];
  }
  contrib = wave_sum(contrib);
  if (lane == 0) wred[wv] = contrib;
  __syncthreads();

  if (tid == 0) {
    const float con = wred[0] + wred[1] + b_bi[0];
    const float n1 = fmaxf(sqrtf(scal[2]), EPS_F);
    const float n2 = fmaxf(sqrtf(scal[1]), EPS_F);
    const float str = scal[0] / (n1 * n2);
    out[c] = (1.f - GAMMA) * str + GAMMA * con;
  }
}

extern "C" void kernel_launch(void* const* d_in, const int* in_sizes, int n_in,
                              void* d_out, int out_size, void* d_ws,
                              size_t ws_size, hipStream_t stream) {
  const float* table = (const float*)d_in[0];
  const float* str_t1 = (const float*)d_in[1];
  const float* str_t2s = (const float*)d_in[2];
  const float* att_mat = (const float*)d_in[3];
  const float* W_bi = (const float*)d_in[4];
  const float* b_bi = (const float*)d_in[5];
  const int* t1_ctx = (const int*)d_in[6];
  const int* t2_ctx = (const int*)d_in[7];
  float* out = (float*)d_out;
  float* AM = (float*)d_ws;  // 64*128 floats = 32 KB scratch

  am_kernel<<<K_CTX, D_DIM, 0, stream>>>(table, att_mat, t1_ctx, AM);
  cand_kernel<<<CAND, 256, 0, stream>>>(table, str_t1, str_t2s, W_bi, b_bi,
                                        t1_ctx, t2_ctx, AM, out);
}

// Round 2
// 592.131 us; speedup vs baseline: 1.0031x; 1.0031x over previous
//
#include <hip/hip_runtime.h>
#include <hip/hip_bf16.h>
#include <math.h>

#define K_CTX 64
#define D_DIM 128
#define DS 200
#define CAND 256
#define EPS_F 1e-8f
#define GAMMA 0.5f

__device__ __forceinline__ float wave_sum(float v) {
#pragma unroll
  for (int o = 32; o > 0; o >>= 1) v += __shfl_xor(v, o, 64);
  return v;
}
__device__ __forceinline__ float wave_max(float v) {
#pragma unroll
  for (int o = 32; o > 0; o >>= 1) v = fmaxf(v, __shfl_xor(v, o, 64));
  return v;
}

// Kernel 1: AM[k][j] = sum_i table[t1_ctx[k]][i] * att_mat[i][j]
__global__ __launch_bounds__(128, 1) void am_kernel(
    const float* __restrict__ table, const float* __restrict__ att_mat,
    const int* __restrict__ t1_ctx, float* __restrict__ AM) {
  __shared__ float sA[D_DIM];
  const int k = blockIdx.x;
  const int j = threadIdx.x;
  const size_t row = (size_t)t1_ctx[k] * D_DIM;
  sA[j] = table[row + j];
  __syncthreads();
  float s = 0.f;
#pragma unroll 8
  for (int i = 0; i < D_DIM; ++i)
    s = fmaf(sA[i], att_mat[(size_t)i * D_DIM + j], s);
  AM[k * D_DIM + j] = s;
}

// Kernel 2: one block per candidate c.
__global__ __launch_bounds__(256, 1) void cand_kernel(
    const float* __restrict__ table, const float* __restrict__ str_t1,
    const float* __restrict__ str_t2s, const float* __restrict__ W_bi,
    const float* __restrict__ b_bi, const int* __restrict__ t1_ctx,
    const int* __restrict__ t2_ctx, const float* __restrict__ AM,
    float* __restrict__ out) {
  const int c = blockIdx.x;
  const int tid = threadIdx.x;
  const int lane = tid & 63;
  const int wv = tid >> 6;  // 0..3

  __shared__ float sAM[K_CTX * D_DIM];  // 32 KB
  __shared__ int t2g[K_CTX];
  __shared__ int t1g[K_CTX];
  __shared__ float colpart[4][K_CTX];
  __shared__ float rowsum[K_CTX];
  __shared__ float rows[K_CTX];
  __shared__ float cols[K_CTX];
  __shared__ float sNA[D_DIM];
  __shared__ float sNB[D_DIM];
  __shared__ float wred[4];
  __shared__ float scal[3];  // str_dot, n2sq, n1sq

  if (tid < K_CTX) {
    t2g[tid] = t2_ctx[c * K_CTX + tid];
    t1g[tid] = t1_ctx[tid];
  }

  // Stage AM into LDS: 2048 float4, 8 per thread (coalesced).
  {
    const float4* amp = (const float4*)AM;
    float4* samp = (float4*)sAM;
#pragma unroll
    for (int t = 0; t < 8; ++t) samp[tid + 256 * t] = amp[tid + 256 * t];
  }
  __syncthreads();

  // S[k][m] = tanh(dot(AM[k], B[m])); lane m holds B row, wave wv handles
  // k in [16*wv, 16*wv+16). B row is processed in 4 chunks of 32 floats to
  // keep register pressure low (8 float4 live at a time, not 32).
  const int m = lane;
  const int kbase = wv * 16;
  const float4* browp = (const float4*)(table + (size_t)t2g[m] * D_DIM);
  const float4* sAM4 = (const float4*)sAM;

  float acc[16];
#pragma unroll
  for (int kk = 0; kk < 16; ++kk) acc[kk] = 0.f;

#pragma unroll
  for (int ch = 0; ch < 4; ++ch) {
    float4 b4[8];
#pragma unroll
    for (int q = 0; q < 8; ++q) b4[q] = browp[ch * 8 + q];
#pragma unroll
    for (int q = 0; q < 8; ++q) {
      const float4 bv = b4[q];
      const int i4 = ch * 8 + q;
#pragma unroll
      for (int kk = 0; kk < 16; ++kk) {
        const float4 am = sAM4[(kbase + kk) * 32 + i4];  // wave-uniform bcast
        acc[kk] = fmaf(am.x, bv.x, acc[kk]);
        acc[kk] = fmaf(am.y, bv.y, acc[kk]);
        acc[kk] = fmaf(am.z, bv.z, acc[kk]);
        acc[kk] = fmaf(am.w, bv.w, acc[kk]);
      }
    }
  }

  float cp = 0.f;
#pragma unroll
  for (int kk = 0; kk < 16; ++kk) {
    const float sv = tanhf(acc[kk]);
    cp += sv;
    const float rs = wave_sum(sv);  // sum over m (64 lanes)
    if (lane == 0) rowsum[kbase + kk] = rs;
  }
  colpart[wv][m] = cp;
  __syncthreads();

  // Softmaxes on waves 0/1; string branch on waves 2/3 (concurrent).
  if (wv == 0) {
    const float rm = rowsum[lane] * (1.f / 64.f);
    const float mx = wave_max(rm);
    const float e = expf(rm - mx);
    const float s = wave_sum(e);
    rows[lane] = e / s;
  } else if (wv == 1) {
    const float csum = colpart[0][lane] + colpart[1][lane] + colpart[2][lane] +
                       colpart[3][lane];
    const float cm = csum * (1.f / 64.f);
    const float mx = wave_max(cm);
    const float e = expf(cm - mx);
    const float s = wave_sum(e);
    cols[lane] = e / s;
  } else if (wv == 2) {
    float dot = 0.f, n2 = 0.f;
    for (int i = lane; i < DS; i += 64) {
      const float a = str_t2s[c * DS + i];
      const float b = str_t1[i];
      dot = fmaf(a, b, dot);
      n2 = fmaf(a, a, n2);
    }
    dot = wave_sum(dot);
    n2 = wave_sum(n2);
    if (lane == 0) { scal[0] = dot; scal[1] = n2; }
  } else {
    float n1 = 0.f;
    for (int i = lane; i < DS; i += 64) {
      const float b = str_t1[i];
      n1 = fmaf(b, b, n1);
    }
    n1 = wave_sum(n1);
    if (lane == 0) scal[2] = n1;
  }
  __syncthreads();

  // new_A[j] = sum_k rows[k]*A[k][j]  (waves 0,1)
  // new_B[j] = sum_m cols[m]*B[m][j]  (waves 2,3) -- table rows L1/L2-hot
  if (tid < 128) {
    const int j = tid;
    float na = 0.f;
#pragma unroll 8
    for (int k = 0; k < K_CTX; ++k)
      na = fmaf(rows[k], table[(size_t)t1g[k] * D_DIM + j], na);
    sNA[j] = na;
  } else {
    const int j = tid - 128;
    float nb = 0.f;
#pragma unroll 8
    for (int mm = 0; mm < K_CTX; ++mm)
      nb = fmaf(cols[mm], table[(size_t)t2g[mm] * D_DIM + j], nb);
    sNB[j] = nb;
  }
  __syncthreads();

  // con = sum_e (sum_d new_A[d]*W[d][e]) * new_B[e]
  float contrib = 0.f;
  if (tid < 128) {
    const int e = tid;
    float t = 0.f;
#pragma unroll 8
    for (int dd = 0; dd < D_DIM; ++dd)
      t = fmaf(sNA[dd], W_bi[dd * D_DIM + e], t);
    contrib = t * sNB[e];
  }
  contrib = wave_sum(contrib);
  if (lane == 0) wred[wv] = contrib;
  __syncthreads();

  if (tid == 0) {
    const float con = wred[0] + wred[1] + b_bi[0];
    const float n1 = fmaxf(sqrtf(scal[2]), EPS_F);
    const float n2 = fmaxf(sqrtf(scal[1]), EPS_F);
    const float str = scal[0] / (n1 * n2);
    out[c] = (1.f - GAMMA) * str + GAMMA * con;
  }
}

extern "C" void kernel_launch(void* const* d_in, const int* in_sizes, int n_in,
                              void* d_out, int out_size, void* d_ws,
                              size_t ws_size, hipStream_t stream) {
  const float* table = (const float*)d_in[0];
  const float* str_t1 = (const float*)d_in[1];
  const float* str_t2s = (const float*)d_in[2];
  const float* att_mat = (const float*)d_in[3];
  const float* W_bi = (const float*)d_in[4];
  const float* b_bi = (const float*)d_in[5];
  const int* t1_ctx = (const int*)d_in[6];
  const int* t2_ctx = (const int*)d_in[7];
  float* out = (float*)d_out;
  float* AM = (float*)d_ws;  // 64*128 floats = 32 KB scratch

  am_kernel<<<K_CTX, D_DIM, 0, stream>>>(table, att_mat, t1_ctx, AM);
  cand_kernel<<<CAND, 256, 0, stream>>>(table, str_t1, str_t2s, W_bi, b_bi,
                                        t1_ctx, t2_ctx, AM, out);
}

// Round 3
// 322.667 us; speedup vs baseline: 1.8408x; 1.8351x over previous
//
#include <hip/hip_runtime.h>
#include <hip/hip_bf16.h>
#include <math.h>

#define K_CTX 64
#define D_DIM 128
#define DS 200
#define CAND 256
#define EPS_F 1e-8f
#define GAMMA 0.5f
#define BSTRIDE 132  // 128 + 4 floats pad -> float4 reads keep stride-1 bank signature

__device__ __forceinline__ float wave_sum(float v) {
#pragma unroll
  for (int o = 32; o > 0; o >>= 1) v += __shfl_xor(v, o, 64);
  return v;
}
__device__ __forceinline__ float wave_max(float v) {
#pragma unroll
  for (int o = 32; o > 0; o >>= 1) v = fmaxf(v, __shfl_xor(v, o, 64));
  return v;
}

// Kernel 1: AM[k] = A[k] @ att_mat, AW[k] = A[k] @ W_bi  (both 64x128)
// new_A @ W_bi == rows @ (A @ W_bi), so the hot kernel never needs A or W_bi.
__global__ __launch_bounds__(128) void pre_kernel(
    const float* __restrict__ table, const float* __restrict__ att_mat,
    const float* __restrict__ W_bi, const int* __restrict__ t1_ctx,
    float* __restrict__ AM, float* __restrict__ AW) {
  __shared__ float sA[D_DIM];
  const int k = blockIdx.x;
  const int j = threadIdx.x;
  sA[j] = table[(size_t)t1_ctx[k] * D_DIM + j];
  __syncthreads();
  float s1 = 0.f, s2 = 0.f;
#pragma unroll 8
  for (int i = 0; i < D_DIM; ++i) {
    const float a = sA[i];
    s1 = fmaf(a, att_mat[(size_t)i * D_DIM + j], s1);
    s2 = fmaf(a, W_bi[(size_t)i * D_DIM + j], s2);
  }
  AM[k * D_DIM + j] = s1;
  AW[k * D_DIM + j] = s2;
}

// Kernel 2: one block (512 threads = 8 waves) per candidate.
__global__ __launch_bounds__(512, 2) void cand_kernel(
    const float* __restrict__ table, const float* __restrict__ str_t1,
    const float* __restrict__ str_t2s, const float* __restrict__ b_bi,
    const int* __restrict__ t2_ctx, const float* __restrict__ AM,
    const float* __restrict__ AW, float* __restrict__ out) {
  const int c = blockIdx.x;
  const int tid = threadIdx.x;
  const int lane = tid & 63;
  const int wv = tid >> 6;  // 0..7

  __shared__ float sB[K_CTX * BSTRIDE];  // 33 KB
  __shared__ float colpart[8][K_CTX];
  __shared__ float rowsum[K_CTX];
  __shared__ float rows[K_CTX];
  __shared__ float cols[K_CTX];
  __shared__ float wred[2];
  __shared__ float scal[3];  // str_dot, n2sq, n1sq

  // --- Stage B rows into LDS (coalesced). thread t -> row t>>3. ---
  {
    const int r = tid >> 3;
    const int q = tid & 7;  // 8 threads per row, 128B contiguous per instr
    const int row_idx = t2_ctx[c * K_CTX + r];
    const float4* src = (const float4*)(table + (size_t)row_idx * D_DIM);
    float4* dst = (float4*)(sB + r * BSTRIDE);
#pragma unroll
    for (int u = 0; u < 4; ++u) dst[q + 8 * u] = src[q + 8 * u];
  }
  __syncthreads();

  // --- S[k][m] = tanh(dot(AM[k], B[m])); wave wv owns k in [8wv, 8wv+8),
  //     lane owns m. AM via wave-uniform scalar loads (SGPR), B from LDS. ---
  const int kb = __builtin_amdgcn_readfirstlane(wv * 8);
  const float* amg = AM + (size_t)kb * D_DIM;
  const float* bp = sB + (size_t)lane * BSTRIDE;

  float acc[8];
#pragma unroll
  for (int kk = 0; kk < 8; ++kk) acc[kk] = 0.f;

#pragma unroll 4
  for (int i4 = 0; i4 < 32; ++i4) {
    const float4 bv = *(const float4*)(bp + 4 * i4);
#pragma unroll
    for (int kk = 0; kk < 8; ++kk) {
      const float4 am = *(const float4*)(amg + kk * D_DIM + 4 * i4);  // s_load
      acc[kk] = fmaf(am.x, bv.x, acc[kk]);
      acc[kk] = fmaf(am.y, bv.y, acc[kk]);
      acc[kk] = fmaf(am.z, bv.z, acc[kk]);
      acc[kk] = fmaf(am.w, bv.w, acc[kk]);
    }
  }

  float cp = 0.f;
#pragma unroll
  for (int kk = 0; kk < 8; ++kk) {
    const float sv = tanhf(acc[kk]);
    cp += sv;
    const float rs = wave_sum(sv);  // sum over m
    if (lane == 0) rowsum[kb + kk] = rs;
  }
  colpart[wv][lane] = cp;
  __syncthreads();

  // --- Softmaxes + string branch, one wave each (concurrent). ---
  if (wv == 0) {
    const float rm = rowsum[lane] * (1.f / 64.f);
    const float mx = wave_max(rm);
    const float e = expf(rm - mx);
    rows[lane] = e / wave_sum(e);
  } else if (wv == 1) {
    float cs = 0.f;
#pragma unroll
    for (int w = 0; w < 8; ++w) cs += colpart[w][lane];
    const float cm = cs * (1.f / 64.f);
    const float mx = wave_max(cm);
    const float e = expf(cm - mx);
    cols[lane] = e / wave_sum(e);
  } else if (wv == 2) {
    float dot = 0.f, n2 = 0.f;
    for (int i = lane; i < DS; i += 64) {
      const float a = str_t2s[c * DS + i];
      const float b = str_t1[i];
      dot = fmaf(a, b, dot);
      n2 = fmaf(a, a, n2);
    }
    dot = wave_sum(dot);
    n2 = wave_sum(n2);
    if (lane == 0) { scal[0] = dot; scal[1] = n2; }
  } else if (wv == 3) {
    float n1 = 0.f;
    for (int i = lane; i < DS; i += 64) {
      const float b = str_t1[i];
      n1 = fmaf(b, b, n1);
    }
    n1 = wave_sum(n1);
    if (lane == 0) scal[2] = n1;
  }
  __syncthreads();

  // --- con = (rows @ AW) . (cols @ B) + b.  threads 0..127 (waves 0,1). ---
  if (tid < 128) {
    const int j = tid;
    float vj = 0.f, nb = 0.f;
#pragma unroll 8
    for (int k = 0; k < K_CTX; ++k) {
      vj = fmaf(rows[k], AW[k * D_DIM + j], vj);       // coalesced global
      nb = fmaf(cols[k], sB[k * BSTRIDE + j], nb);     // conflict-free LDS
    }
    const float contrib = wave_sum(vj * nb);
    if (lane == 0) wred[wv] = contrib;
  }
  __syncthreads();

  if (tid == 0) {
    const float con = wred[0] + wred[1] + b_bi[0];
    const float n1 = fmaxf(sqrtf(scal[2]), EPS_F);
    const float n2 = fmaxf(sqrtf(scal[1]), EPS_F);
    const float str = scal[0] / (n1 * n2);
    out[c] = (1.f - GAMMA) * str + GAMMA * con;
  }
}

extern "C" void kernel_launch(void* const* d_in, const int* in_sizes, int n_in,
                              void* d_out, int out_size, void* d_ws,
                              size_t ws_size, hipStream_t stream) {
  const float* table = (const float*)d_in[0];
  const float* str_t1 = (const float*)d_in[1];
  const float* str_t2s = (const float*)d_in[2];
  const float* att_mat = (const float*)d_in[3];
  const float* W_bi = (const float*)d_in[4];
  const float* b_bi = (const float*)d_in[5];
  const int* t1_ctx = (const int*)d_in[6];
  const int* t2_ctx = (const int*)d_in[7];
  float* out = (float*)d_out;
  float* AM = (float*)d_ws;                     // 64*128 floats = 32 KB
  float* AW = (float*)d_ws + K_CTX * D_DIM;     // next 32 KB

  pre_kernel<<<K_CTX, D_DIM, 0, stream>>>(table, att_mat, W_bi, t1_ctx, AM, AW);
  cand_kernel<<<CAND, 512, 0, stream>>>(table, str_t1, str_t2s, b_bi, t2_ctx,
                                        AM, AW, out);
}

// Round 4
// 317.823 us; speedup vs baseline: 1.8688x; 1.0152x over previous
//
#include <hip/hip_runtime.h>
#include <hip/hip_bf16.h>
#include <math.h>

#define K_CTX 64
#define D_DIM 128
#define DS 200
#define CAND 256
#define EPS_F 1e-8f
#define GAMMA 0.5f
#define BSTRIDE 132  // 128+4 pad: lane-varying b128 reads tile banks in the minimal 8 phases

__device__ __forceinline__ float wave_sum(float v) {
#pragma unroll
  for (int o = 32; o > 0; o >>= 1) v += __shfl_xor(v, o, 64);
  return v;
}
__device__ __forceinline__ float wave_max(float v) {
#pragma unroll
  for (int o = 32; o > 0; o >>= 1) v = fmaxf(v, __shfl_xor(v, o, 64));
  return v;
}

// Kernel 1: AM[k] = A[k] @ att_mat, AW[k] = A[k] @ W_bi  (both 64x128)
// new_A @ W_bi == rows @ (A @ W_bi): hot kernel never touches A or W_bi.
__global__ __launch_bounds__(128) void pre_kernel(
    const float* __restrict__ table, const float* __restrict__ att_mat,
    const float* __restrict__ W_bi, const int* __restrict__ t1_ctx,
    float* __restrict__ AM, float* __restrict__ AW) {
  __shared__ float sA[D_DIM];
  const int k = blockIdx.x;
  const int j = threadIdx.x;
  sA[j] = table[(size_t)t1_ctx[k] * D_DIM + j];
  __syncthreads();
  float s1 = 0.f, s2 = 0.f;
#pragma unroll 8
  for (int i = 0; i < D_DIM; ++i) {
    const float a = sA[i];
    s1 = fmaf(a, att_mat[(size_t)i * D_DIM + j], s1);
    s2 = fmaf(a, W_bi[(size_t)i * D_DIM + j], s2);
  }
  AM[k * D_DIM + j] = s1;
  AW[k * D_DIM + j] = s2;
}

// Kernel 2: one block (512 threads = 8 waves) per candidate.
// Pure-LDS main loop: no SMEM/DS lgkmcnt mixing, no register B-cache.
__global__ __launch_bounds__(512, 2) void cand_kernel(
    const float* __restrict__ table, const float* __restrict__ str_t1,
    const float* __restrict__ str_t2s, const float* __restrict__ b_bi,
    const int* __restrict__ t2_ctx, const float* __restrict__ AM,
    const float* __restrict__ AW, float* __restrict__ out) {
  const int c = blockIdx.x;
  const int tid = threadIdx.x;
  const int lane = tid & 63;
  const int wv = tid >> 6;  // 0..7

  __shared__ float sAM[K_CTX * D_DIM];   // 32 KB, broadcast-read (conflict-free)
  __shared__ float sB[K_CTX * BSTRIDE];  // 33 KB, lane-varying reads (8-phase)
  __shared__ float colpart[8][K_CTX];
  __shared__ float rowsum[K_CTX];
  __shared__ float rows[K_CTX];
  __shared__ float cols[K_CTX];
  __shared__ float wred[2];
  __shared__ float scal[3];  // str_dot, n2sq, n1sq

  // --- Stage B rows (gather) and AM (coalesced, L2-hot) into LDS. ---
  {
    const int r = tid >> 3;
    const int q = tid & 7;  // 8 threads per row -> 128B contiguous per instr
    const int row_idx = t2_ctx[c * K_CTX + r];
    const float4* src = (const float4*)(table + (size_t)row_idx * D_DIM);
    float4* dst = (float4*)(sB + r * BSTRIDE);
#pragma unroll
    for (int u = 0; u < 4; ++u) dst[q + 8 * u] = src[q + 8 * u];

    const float4* amp = (const float4*)AM;  // 2048 float4 total
    float4* samp = (float4*)sAM;
#pragma unroll
    for (int t = 0; t < 4; ++t) samp[tid + 512 * t] = amp[tid + 512 * t];
  }
  __syncthreads();

  // --- S[k][m] = tanh(dot(AM[k], B[m])); wave wv owns k in [8wv,8wv+8),
  //     lane owns m. Both operands from LDS: AM broadcast, B lane-varying. ---
  const int kb = wv * 8;
  const float* bp = sB + (size_t)lane * BSTRIDE;
  const float4* sAM4 = (const float4*)sAM;

  float acc[8];
#pragma unroll
  for (int kk = 0; kk < 8; ++kk) acc[kk] = 0.f;

#pragma unroll 4
  for (int i4 = 0; i4 < 32; ++i4) {
    const float4 bv = *(const float4*)(bp + 4 * i4);
#pragma unroll
    for (int kk = 0; kk < 8; ++kk) {
      const float4 am = sAM4[(kb + kk) * 32 + i4];  // wave-uniform broadcast
      acc[kk] = fmaf(am.x, bv.x, acc[kk]);
      acc[kk] = fmaf(am.y, bv.y, acc[kk]);
      acc[kk] = fmaf(am.z, bv.z, acc[kk]);
      acc[kk] = fmaf(am.w, bv.w, acc[kk]);
    }
  }

  float cp = 0.f;
#pragma unroll
  for (int kk = 0; kk < 8; ++kk) {
    const float sv = tanhf(acc[kk]);
    cp += sv;
    const float rs = wave_sum(sv);  // sum over m
    if (lane == 0) rowsum[kb + kk] = rs;
  }
  colpart[wv][lane] = cp;
  __syncthreads();

  // --- Softmaxes + string branch, one wave each (concurrent). ---
  if (wv == 0) {
    const float rm = rowsum[lane] * (1.f / 64.f);
    const float mx = wave_max(rm);
    const float e = expf(rm - mx);
    rows[lane] = e / wave_sum(e);
  } else if (wv == 1) {
    float cs = 0.f;
#pragma unroll
    for (int w = 0; w < 8; ++w) cs += colpart[w][lane];
    const float cm = cs * (1.f / 64.f);
    const float mx = wave_max(cm);
    const float e = expf(cm - mx);
    cols[lane] = e / wave_sum(e);
  } else if (wv == 2) {
    float dot = 0.f, n2 = 0.f;
    for (int i = lane; i < DS; i += 64) {
      const float a = str_t2s[c * DS + i];
      const float b = str_t1[i];
      dot = fmaf(a, b, dot);
      n2 = fmaf(a, a, n2);
    }
    dot = wave_sum(dot);
    n2 = wave_sum(n2);
    if (lane == 0) { scal[0] = dot; scal[1] = n2; }
  } else if (wv == 3) {
    float n1 = 0.f;
    for (int i = lane; i < DS; i += 64) {
      const float b = str_t1[i];
      n1 = fmaf(b, b, n1);
    }
    n1 = wave_sum(n1);
    if (lane == 0) scal[2] = n1;
  }
  __syncthreads();

  // --- con = (rows @ AW) . (cols @ B) + b.  threads 0..127 (waves 0,1). ---
  if (tid < 128) {
    const int j = tid;
    float vj = 0.f, nb = 0.f;
#pragma unroll 8
    for (int k = 0; k < K_CTX; ++k) {
      vj = fmaf(rows[k], AW[k * D_DIM + j], vj);    // coalesced global, L2-hot
      nb = fmaf(cols[k], sB[k * BSTRIDE + j], nb);  // 2-way LDS alias (free)
    }
    const float contrib = wave_sum(vj * nb);
    if (lane == 0) wred[wv] = contrib;
  }
  __syncthreads();

  if (tid == 0) {
    const float con = wred[0] + wred[1] + b_bi[0];
    const float n1 = fmaxf(sqrtf(scal[2]), EPS_F);
    const float n2 = fmaxf(sqrtf(scal[1]), EPS_F);
    const float str = scal[0] / (n1 * n2);
    out[c] = (1.f - GAMMA) * str + GAMMA * con;
  }
}

extern "C" void kernel_launch(void* const* d_in, const int* in_sizes, int n_in,
                              void* d_out, int out_size, void* d_ws,
                              size_t ws_size, hipStream_t stream) {
  const float* table = (const float*)d_in[0];
  const float* str_t1 = (const float*)d_in[1];
  const float* str_t2s = (const float*)d_in[2];
  const float* att_mat = (const float*)d_in[3];
  const float* W_bi = (const float*)d_in[4];
  const float* b_bi = (const float*)d_in[5];
  const int* t1_ctx = (const int*)d_in[6];
  const int* t2_ctx = (const int*)d_in[7];
  float* out = (float*)d_out;
  float* AM = (float*)d_ws;                  // 64*128 floats = 32 KB
  float* AW = (float*)d_ws + K_CTX * D_DIM;  // next 32 KB

  pre_kernel<<<K_CTX, D_DIM, 0, stream>>>(table, att_mat, W_bi, t1_ctx, AM, AW);
  cand_kernel<<<CAND, 512, 0, stream>>>(table, str_t1, str_t2s, b_bi, t2_ctx,
                                        AM, AW, out);
}

// Round 5
// 316.705 us; speedup vs baseline: 1.8754x; 1.0035x over previous
//
#include <hip/hip_runtime.h>
#include <hip/hip_bf16.h>
#include <math.h>

#define K_CTX 64
#define D_DIM 128
#define DS 200
#define CAND 256
#define EPS_F 1e-8f
#define GAMMA 0.5f
#define BSTRIDE 132  // 128+4 pad: lane-varying b128 reads keep the stride-1 bank signature

__device__ __forceinline__ float wave_sum(float v) {
#pragma unroll
  for (int o = 32; o > 0; o >>= 1) v += __shfl_xor(v, o, 64);
  return v;
}
__device__ __forceinline__ float wave_max(float v) {
#pragma unroll
  for (int o = 32; o > 0; o >>= 1) v = fmaxf(v, __shfl_xor(v, o, 64));
  return v;
}
// tanh via hardware v_exp_f32: 1 - 2/(e^{2x}+1). Saturates correctly at +/-inf.
__device__ __forceinline__ float fast_tanh(float x) {
  const float e = __expf(2.f * x);
  return 1.f - 2.f / (e + 1.f);
}

// Kernel 1: AM[k] = A[k] @ att_mat, AW[k] = A[k] @ W_bi  (both 64x128).
// new_A @ W_bi == rows @ (A @ W_bi): hot kernel never touches A or W_bi.
// 128 blocks x 64 threads: block (k, j-half), one full wave each.
__global__ __launch_bounds__(64) void pre_kernel(
    const float* __restrict__ table, const float* __restrict__ att_mat,
    const float* __restrict__ W_bi, const int* __restrict__ t1_ctx,
    float* __restrict__ AM, float* __restrict__ AW) {
  __shared__ float sA[D_DIM];
  const int k = blockIdx.x >> 1;
  const int h = blockIdx.x & 1;
  const int t = threadIdx.x;  // 0..63
  const int j = h * 64 + t;
  const size_t arow = (size_t)t1_ctx[k] * D_DIM;
  sA[t] = table[arow + t];
  sA[t + 64] = table[arow + t + 64];
  __syncthreads();
  float s1 = 0.f, s2 = 0.f;
#pragma unroll 8
  for (int i = 0; i < D_DIM; ++i) {
    const float a = sA[i];
    s1 = fmaf(a, att_mat[(size_t)i * D_DIM + j], s1);
    s2 = fmaf(a, W_bi[(size_t)i * D_DIM + j], s2);
  }
  AM[k * D_DIM + j] = s1;
  AW[k * D_DIM + j] = s2;
}

// Kernel 2: one block (512 threads = 8 waves) per candidate.
// Pure-LDS main loop: AM broadcast (conflict-free), B lane-varying (8-phase min).
__global__ __launch_bounds__(512, 2) void cand_kernel(
    const float* __restrict__ table, const float* __restrict__ str_t1,
    const float* __restrict__ str_t2s, const float* __restrict__ b_bi,
    const int* __restrict__ t2_ctx, const float* __restrict__ AM,
    const float* __restrict__ AW, float* __restrict__ out) {
  const int c = blockIdx.x;
  const int tid = threadIdx.x;
  const int lane = tid & 63;
  const int wv = tid >> 6;  // 0..7

  __shared__ float sAM[K_CTX * D_DIM];   // 32 KB
  __shared__ float sB[K_CTX * BSTRIDE];  // 33 KB
  __shared__ float colpart[8][K_CTX];
  __shared__ float rowsum[K_CTX];
  __shared__ float rows[K_CTX];
  __shared__ float cols[K_CTX];
  __shared__ float wred[2];
  __shared__ float scal[3];  // str_dot, n2sq, n1sq

  // --- Stage B rows (gather) and AM (coalesced, L2-hot) into LDS. ---
  {
    const int r = tid >> 3;
    const int q = tid & 7;  // 8 threads per row -> 128B contiguous per instr
    const int row_idx = t2_ctx[c * K_CTX + r];
    const float4* src = (const float4*)(table + (size_t)row_idx * D_DIM);
    float4* dst = (float4*)(sB + r * BSTRIDE);
#pragma unroll
    for (int u = 0; u < 4; ++u) dst[q + 8 * u] = src[q + 8 * u];

    const float4* amp = (const float4*)AM;  // 2048 float4 total
    float4* samp = (float4*)sAM;
#pragma unroll
    for (int t = 0; t < 4; ++t) samp[tid + 512 * t] = amp[tid + 512 * t];
  }
  __syncthreads();

  // --- S[k][m] = tanh(dot(AM[k], B[m])); wave wv owns k in [8wv,8wv+8),
  //     lane owns m. ---
  const int kb = wv * 8;
  const float* bp = sB + (size_t)lane * BSTRIDE;
  const float4* sAM4 = (const float4*)sAM;

  float acc[8];
#pragma unroll
  for (int kk = 0; kk < 8; ++kk) acc[kk] = 0.f;

#pragma unroll 4
  for (int i4 = 0; i4 < 32; ++i4) {
    const float4 bv = *(const float4*)(bp + 4 * i4);
#pragma unroll
    for (int kk = 0; kk < 8; ++kk) {
      const float4 am = sAM4[(kb + kk) * 32 + i4];  // wave-uniform broadcast
      acc[kk] = fmaf(am.x, bv.x, acc[kk]);
      acc[kk] = fmaf(am.y, bv.y, acc[kk]);
      acc[kk] = fmaf(am.z, bv.z, acc[kk]);
      acc[kk] = fmaf(am.w, bv.w, acc[kk]);
    }
  }

  float cp = 0.f;
#pragma unroll
  for (int kk = 0; kk < 8; ++kk) {
    const float sv = fast_tanh(acc[kk]);
    cp += sv;
    const float rs = wave_sum(sv);  // sum over m
    if (lane == 0) rowsum[kb + kk] = rs;
  }
  colpart[wv][lane] = cp;
  __syncthreads();

  // --- Softmaxes + string branch, one wave each (concurrent). ---
  if (wv == 0) {
    const float rm = rowsum[lane] * (1.f / 64.f);
    const float mx = wave_max(rm);
    const float e = __expf(rm - mx);
    rows[lane] = e / wave_sum(e);
  } else if (wv == 1) {
    float cs = 0.f;
#pragma unroll
    for (int w = 0; w < 8; ++w) cs += colpart[w][lane];
    const float cm = cs * (1.f / 64.f);
    const float mx = wave_max(cm);
    const float e = __expf(cm - mx);
    cols[lane] = e / wave_sum(e);
  } else if (wv == 2) {
    float dot = 0.f, n2 = 0.f;
    for (int i = lane; i < DS; i += 64) {
      const float a = str_t2s[c * DS + i];
      const float b = str_t1[i];
      dot = fmaf(a, b, dot);
      n2 = fmaf(a, a, n2);
    }
    dot = wave_sum(dot);
    n2 = wave_sum(n2);
    if (lane == 0) { scal[0] = dot; scal[1] = n2; }
  } else if (wv == 3) {
    float n1 = 0.f;
    for (int i = lane; i < DS; i += 64) {
      const float b = str_t1[i];
      n1 = fmaf(b, b, n1);
    }
    n1 = wave_sum(n1);
    if (lane == 0) scal[2] = n1;
  }
  __syncthreads();

  // --- con = (rows @ AW) . (cols @ B) + b.  threads 0..127 (waves 0,1). ---
  if (tid < 128) {
    const int j = tid;
    float vj = 0.f, nb = 0.f;
#pragma unroll 8
    for (int k = 0; k < K_CTX; ++k) {
      vj = fmaf(rows[k], AW[k * D_DIM + j], vj);    // coalesced global, L2-hot
      nb = fmaf(cols[k], sB[k * BSTRIDE + j], nb);  // 2-way LDS alias (free)
    }
    const float contrib = wave_sum(vj * nb);
    if (lane == 0) wred[wv] = contrib;
  }
  __syncthreads();

  if (tid == 0) {
    const float con = wred[0] + wred[1] + b_bi[0];
    const float n1 = fmaxf(sqrtf(scal[2]), EPS_F);
    const float n2 = fmaxf(sqrtf(scal[1]), EPS_F);
    const float str = scal[0] / (n1 * n2);
    out[c] = (1.f - GAMMA) * str + GAMMA * con;
  }
}

extern "C" void kernel_launch(void* const* d_in, const int* in_sizes, int n_in,
                              void* d_out, int out_size, void* d_ws,
                              size_t ws_size, hipStream_t stream) {
  const float* table = (const float*)d_in[0];
  const float* str_t1 = (const float*)d_in[1];
  const float* str_t2s = (const float*)d_in[2];
  const float* att_mat = (const float*)d_in[3];
  const float* W_bi = (const float*)d_in[4];
  const float* b_bi = (const float*)d_in[5];
  const int* t1_ctx = (const int*)d_in[6];
  const int* t2_ctx = (const int*)d_in[7];
  float* out = (float*)d_out;
  float* AM = (float*)d_ws;                  // 64*128 floats = 32 KB
  float* AW = (float*)d_ws + K_CTX * D_DIM;  // next 32 KB

  pre_kernel<<<2 * K_CTX, 64, 0, stream>>>(table, att_mat, W_bi, t1_ctx, AM, AW);
  cand_kernel<<<CAND, 512, 0, stream>>>(table, str_t1, str_t2s, b_bi, t2_ctx,
                                        AM, AW, out);
}